// Round 11
// baseline (144.302 us; speedup 1.0000x reference)
//
#include <hip/hip_runtime.h>

#define SS 730
#define GG 4000
#define LENF 15
#define PD 10          // prefetch depth (steps); 730 % 10 == 0
#define GPAD 4032      // 63 waves per model -> no wave mixes models
#define TT 10          // route time-tile; 730 % 10 == 0
#define QN ((size_t)SS * GG)
#define QNI ((int)(SS * GG))

// Packed fp32 pair: lane-local SIMD over the two NMUL multipliers.
// gfx950 lowers <2 x float> add/mul/fma to v_pk_{add,mul,fma}_f32 (VOP3P),
// advancing BOTH multiplier chains in one issue slot -- structural ILP the
// wave scheduler cannot serialize (rounds 4/8 showed it serializes separate
// scalar chains). min/max/exp2/log2 have no packed f32 form and scalarize
// to adjacent pairs (still interleaved, dep-gap halved).
typedef float v2 __attribute__((ext_vector_type(2)));
static __device__ __forceinline__ v2 vmin(v2 a, v2 b) {
    v2 r; r.x = fminf(a.x, b.x); r.y = fminf(a.y, b.y); return r;
}
static __device__ __forceinline__ v2 vmax(v2 a, v2 b) {
    v2 r; r.x = fmaxf(a.x, b.x); r.y = fmaxf(a.y, b.y); return r;
}
static __device__ __forceinline__ v2 vmax0(v2 a) {
    v2 r; r.x = fmaxf(a.x, 0.0f); r.y = fmaxf(a.y, 0.0f); return r;
}
static __device__ __forceinline__ v2 vexp2(v2 a) {
    v2 r; r.x = exp2f(a.x); r.y = exp2f(a.y); return r;
}
static __device__ __forceinline__ v2 vlog2(v2 a) {
    v2 r; r.x = __log2f(a.x); r.y = __log2f(a.y); return r;
}

// ---------------------------------------------------------------------------
// Scan kernel: one thread per (cell g, model), both multipliers packed.
// model = tid/GPAD: 0 -> HBV, 1 -> EXP. Stores qm0+qm1 into slice[model]
// (2 slices). Round-7 algebraic chain trims retained. PD-deep register
// prefetch of the (shared) forcing hides HBM/L3 latency.
// ---------------------------------------------------------------------------
template<bool STORE2>
__global__ __launch_bounds__(64, 1) void hydro_scan(const float* __restrict__ x,
                                                    const float* __restrict__ raw,
                                                    float* __restrict__ qsim) {
    int tid = blockIdx.x * 64 + threadIdx.x;
    int g = tid % GPAD;
    int model = tid / GPAD;
    if (g >= GG) return;
    // prv[i] = {raw[g,2i], raw[g,2i+1]} : param i for multipliers m=0,1.
    // 8-byte aligned: g*38*4 = g*152, 152 % 8 == 0.
    const v2* prv = reinterpret_cast<const v2*>(raw + (size_t)g * 38);

    int xoff = g * 3;
    int qoff = g + (STORE2 ? model * QNI : 0);

    // prefetch pipeline: steps 0..PD-1 (forcing shared by both multipliers)
    float pb[PD], tb[PD], eb[PD];
#pragma unroll
    for (int j = 0; j < PD; ++j) {
        pb[j] = x[xoff]; tb[j] = x[xoff + 1]; eb[j] = x[xoff + 2];
        xoff += 3 * GG;
    }

    if (model == 0) {
        // ---- HBV parameters (descale + derived constants), packed ----
        v2 beta  = 1.0f   + prv[0]  * 5.0f;
        v2 fc    = 50.0f  + prv[1]  * 950.0f;
        v2 k0    = 0.05f  + prv[2]  * 0.85f;
        v2 k1    = 0.01f  + prv[3]  * 0.49f;
        v2 k2    = 0.001f + prv[4]  * 0.199f;
        v2 lp    = 0.2f   + prv[5]  * 0.8f;
        v2 perc  =          prv[6]  * 10.0f;
        v2 uzl   =          prv[7]  * 100.0f;
        v2 tt    = -2.5f  + prv[8]  * 5.0f;
        v2 cfmax = 0.5f   + prv[9]  * 9.5f;
        v2 cfr   =          prv[10] * 0.1f;
        v2 cwh   =          prv[11] * 0.2f;
        v2 invfc;   invfc.x = 1.0f / fc.x;  invfc.y = 1.0f / fc.y;
        v2 invlpfc; invlpfc.x = 1.0f / (lp.x * fc.x); invlpfc.y = 1.0f / (lp.y * fc.y);
        v2 ncfrcf = -(cfr * cfmax);
        v2 omk0   = 1.0f - k0;
        v2 k0uzl  = k0 * uzl;
        v2 omk1   = 1.0f - k1;

        v2 sp = {1e-5f, 1e-5f}, mw = {1e-5f, 1e-5f};
        v2 sm = 0.5f * fc;
        v2 suz = {1e-5f, 1e-5f}, slz = {1e-5f, 1e-5f};

        auto body = [&](float p, float tc, float pet) -> float {
            // off-chain (forcing/param-only) terms
            v2 dt   = tc - tt;
            v2 msn  = vmax0(cfmax * dt);
            v2 mrf  = vmax0(ncfrcf * dt);
            v2 rain; rain.x = (dt.x >= 0.0f) ? p : 0.0f;
                     rain.y = (dt.y >= 0.0f) ? p : 0.0f;
            v2 snow = p - rain;
            v2 etk  = 1.0f - invlpfc * pet;
            // long pole: sw from previous-step sm
            v2 sw   = vexp2(beta * vlog2(sm * invfc));   // <= 1 (sm<=fc)
            v2 omsw = 1.0f - sw;
            // snow / melt-water chains
            v2 sp1  = sp + snow;
            v2 melt = vmin(msn, sp1);
            v2 mw2  = mw + melt;
            v2 sp2  = sp1 - melt;
            v2 refr = vmin(mrf, mw2);
            v2 mw3  = mw2 - refr;
            sp = sp2 + refr;
            v2 mw4  = vmin(mw3, cwh * sp);
            v2 tosoil = mw3 - mw4;
            mw = mw4;
            // soil moisture
            v2 rt     = rain + tosoil;
            v2 sm1    = sm + rt * omsw;
            v2 rech   = rt * sw;
            v2 excess = vmax0(sm1 - fc);
            v2 sm2    = vmin(sm1, fc);
            v2 smlo   = {1e-5f, 1e-5f};
            sm = vmax(vmax(sm2 * etk, sm2 - pet), smlo);
            // upper / lower zones
            v2 suz1 = suz + rech + excess;
            v2 suz2 = vmax0(suz1 - perc);
            v2 pa   = suz1 - suz2;
            v2 suz3 = vmin(suz2, suz2 * omk0 + k0uzl);
            v2 suzn = omk1 * suz3;
            v2 q01  = suz2 - suzn;
            suz = suzn;
            v2 slz1 = slz + pa;
            v2 q2   = k2 * slz1;
            slz = slz1 - q2;
            v2 q = q01 + q2;
            return q.x + q.y;
        };

        for (int c = 0; c < SS / PD - 1; ++c) {
#pragma unroll
            for (int j = 0; j < PD; ++j) {
                float p = pb[j], tc = tb[j], pet = eb[j];
                pb[j] = x[xoff]; tb[j] = x[xoff + 1]; eb[j] = x[xoff + 2];
                xoff += 3 * GG;
                float q = body(p, tc, pet);
                if (STORE2) qsim[qoff] = q; else atomicAdd(&qsim[qoff], 0.25f * q);
                qoff += GG;
            }
        }
#pragma unroll
        for (int j = 0; j < PD; ++j) {           // peeled last chunk
            float q = body(pb[j], tb[j], eb[j]);
            if (STORE2) qsim[qoff] = q; else atomicAdd(&qsim[qoff], 0.25f * q);
            qoff += GG;
        }
    } else {
        // ---- EXP-HYDRO parameters (descale + derived constants), packed ----
        v2 f    =           prv[12] * 0.1f;
        v2 smax = 100.0f  + prv[13] * 1400.0f;
        v2 qmax = 10.0f   + prv[14] * 40.0f;
        v2 df   =           prv[15] * 5.0f;
        v2 tmax =           prv[16] * 3.0f;
        v2 tmin = -3.0f   + prv[17] * 3.0f;
        v2 invsmax; invsmax.x = 1.0f / smax.x; invsmax.y = 1.0f / smax.y;
        v2 fl = f * 1.44269504f;                 // f * log2(e)
        v2 c0; c0.x = __log2f(qmax.x) - fl.x * smax.x;   // fold qmax into exp2
               c0.y = __log2f(qmax.y) - fl.y * smax.y;

        v2 s0 = {1e-5f, 1e-5f};
        v2 s1 = 0.5f * smax;

        auto body = [&](float p, float tc, float pet) -> float {
            // off-chain terms
            v2 mdf = df * vmax0(tc - tmax);
            v2 ps; ps.x = (tc <= tmin.x) ? p : 0.0f;
                   ps.y = (tc <= tmin.y) ? p : 0.0f;
            v2 prr = p - ps;
            v2 etk = vmax0(1.0f - invsmax * pet);
            // chains
            v2 mlt = vmin(s0, mdf);
            s0 = vmax0(s0 - mdf) + ps;
            v2 s1a = s1 + prr + mlt;
            v2 qspill = vmax0(s1a - smax);
            v2 s1b = vmin(s1a, smax);
            v2 s1c = s1b * etk;                  // s1b - et (exact)
            v2 qb  = vmin(vexp2(fl * s1c + c0), s1c);
            s1 = s1c - qb;
            v2 q = qspill + qb;
            return q.x + q.y;
        };

        for (int c = 0; c < SS / PD - 1; ++c) {
#pragma unroll
            for (int j = 0; j < PD; ++j) {
                float p = pb[j], tc = tb[j], pet = eb[j];
                pb[j] = x[xoff]; tb[j] = x[xoff + 1]; eb[j] = x[xoff + 2];
                xoff += 3 * GG;
                float q = body(p, tc, pet);
                if (STORE2) qsim[qoff] = q; else atomicAdd(&qsim[qoff], 0.25f * q);
                qoff += GG;
            }
        }
#pragma unroll
        for (int j = 0; j < PD; ++j) {
            float q = body(pb[j], tb[j], eb[j]);
            if (STORE2) qsim[qoff] = q; else atomicAdd(&qsim[qoff], 0.25f * q);
            qoff += GG;
        }
    }
}

// ---------------------------------------------------------------------------
// UH weights: one thread per g, 15 normalized gamma-UH weights once (0.25
// folded). gammaln cancels: w[k] ∝ exp((aa-1)ln(k+.5)-(k+.5)/th).
// ---------------------------------------------------------------------------
__global__ __launch_bounds__(256) void uh_weights(const float* __restrict__ raw,
                                                  float* __restrict__ wbuf) {
    int g = blockIdx.x * 256 + threadIdx.x;
    if (g >= GG) return;
    float a = raw[(size_t)g * 38 + 36] * 2.9f;
    float b = raw[(size_t)g * 38 + 37] * 6.5f;
    float aa = fmaxf(a, 0.0f) + 0.1f;
    float th = fmaxf(b, 0.0f) + 0.5f;
    float am1 = aa - 1.0f;
    float invth = 1.0f / th;

    const float logt[LENF] = {
        -0.69314718f, 0.40546511f, 0.91629073f, 1.25276297f, 1.50407740f,
         1.70474809f, 1.87180218f, 2.01490302f, 2.14006616f, 2.25129180f,
         2.35137526f, 2.44234704f, 2.52572864f, 2.60268969f, 2.67414865f };

    float w[LENF];
    float s = 0.0f;
#pragma unroll
    for (int k = 0; k < LENF; ++k) {
        float tk = (float)k + 0.5f;
        w[k] = expf(am1 * logt[k] - tk * invth);
        s += w[k];
    }
    float scale = 0.25f / s;
#pragma unroll
    for (int k = 0; k < LENF; ++k)
        wbuf[(size_t)k * GG + g] = w[k] * scale;
}

// ---------------------------------------------------------------------------
// Routing kernel, t-tiled: each thread owns one g and TT consecutive t's.
// WPRE: weights preloaded from wbuf (scale folded). NB = #qsim slices summed.
// ---------------------------------------------------------------------------
template<int NB, bool WPRE>
__global__ __launch_bounds__(256) void hydro_route(const float* __restrict__ qsim,
                                                   const float* __restrict__ raw,
                                                   const float* __restrict__ wbuf,
                                                   float* __restrict__ out) {
    int idx = blockIdx.x * 256 + threadIdx.x;
    if (idx >= GG * (SS / TT)) return;
    int g = idx % GG;          // g fast -> coalesced
    int c = idx / GG;
    int t0 = c * TT;

    float w[LENF];
    float scale;
    if (WPRE) {
#pragma unroll
        for (int k = 0; k < LENF; ++k)
            w[k] = wbuf[(size_t)k * GG + g];
        scale = 1.0f;
    } else {
        float a = raw[(size_t)g * 38 + 36] * 2.9f;
        float b = raw[(size_t)g * 38 + 37] * 6.5f;
        float aa = fmaxf(a, 0.0f) + 0.1f;
        float th = fmaxf(b, 0.0f) + 0.5f;
        float am1 = aa - 1.0f;
        float invth = 1.0f / th;
        const float logt[LENF] = {
            -0.69314718f, 0.40546511f, 0.91629073f, 1.25276297f, 1.50407740f,
             1.70474809f, 1.87180218f, 2.01490302f, 2.14006616f, 2.25129180f,
             2.35137526f, 2.44234704f, 2.52572864f, 2.60268969f, 2.67414865f };
        float s = 0.0f;
#pragma unroll
        for (int k = 0; k < LENF; ++k) {
            float tk = (float)k + 0.5f;
            w[k] = expf(am1 * logt[k] - tk * invth);
            s += w[k];
        }
        scale = (NB == 2 ? 0.25f : 1.0f) / s;
    }

    // load qsim[t0-14 .. t0+TT-1] (zeros before t=0), summing NB slices
    float v[TT + LENF - 1];
#pragma unroll
    for (int i = 0; i < TT + LENF - 1; ++i) {
        int tp = t0 - (LENF - 1) + i;
        float sv = 0.0f;
        if (tp >= 0) {
            const float* qb = qsim + (size_t)tp * GG + g;
            sv = qb[0];
            if (NB == 2) sv += qb[QN];
        }
        v[i] = sv;
    }
#pragma unroll
    for (int j = 0; j < TT; ++j) {
        float acc = 0.0f;
#pragma unroll
        for (int k = 0; k < LENF; ++k)
            acc += w[k] * v[j + (LENF - 1) - k];
        out[(size_t)(t0 + j) * GG + g] = (WPRE ? acc : acc * scale);
    }
}

// ---------------------------------------------------------------------------
extern "C" void kernel_launch(void* const* d_in, const int* in_sizes, int n_in,
                              void* d_out, int out_size, void* d_ws, size_t ws_size,
                              hipStream_t stream) {
    const float* x   = (const float*)d_in[0];   // (730, 4000, 3) f32
    const float* raw = (const float*)d_in[1];   // (4000, 38) f32
    float* out  = (float*)d_out;                // (730, 4000) f32
    float* qsim = (float*)d_ws;

    const size_t slices2 = 2 * QN * sizeof(float);
    const size_t wbytes  = (size_t)LENF * GG * sizeof(float);
    int rblocks = (GG * (SS / TT) + 255) / 256;
    int sblocks = (2 * GPAD) / 64;

    if (ws_size >= slices2 + wbytes) {
        float* wbuf = qsim + 2 * QN;
        hydro_scan<true><<<sblocks, 64, 0, stream>>>(x, raw, qsim);
        uh_weights<<<(GG + 255) / 256, 256, 0, stream>>>(raw, wbuf);
        hydro_route<2, true><<<rblocks, 256, 0, stream>>>(qsim, raw, wbuf, out);
    } else {
        hipMemsetAsync(qsim, 0, QN * sizeof(float), stream);
        hydro_scan<false><<<sblocks, 64, 0, stream>>>(x, raw, qsim);
        hydro_route<1, false><<<rblocks, 256, 0, stream>>>(qsim, raw, nullptr, out);
    }
}

// Round 12
// 128.032 us; speedup vs baseline: 1.1271x; 1.1271x over previous
//
#include <hip/hip_runtime.h>

#define SS 730
#define GG 4000
#define LENF 15
#define PD 10          // prefetch depth (steps); 730 % 10 == 0
#define GPAD 4032      // 63 waves per instance -> no wave mixes models
#define TT 73          // route time-tile; 730 = 73 * 10
#define QN ((size_t)SS * GG)
#define QNI ((int)(SS * GG))

// ---------------------------------------------------------------------------
// Scan kernel: round-7 exact revert (best measured: ~89 us). One thread per
// (cell g, multiplier m, model), SPLIT topology. inst = tid/GPAD:
// 0,1 -> HBV (m=inst&1); 2,3 -> EXP (m=inst&1). Algebraic chain trims:
// off-chain clip bounds, collapsed sub/max pairs, max3 ET update, qmax
// folded into exp2, 32-bit offsets. PD-deep register prefetch.
// Four rounds of ILP experiments (4,8,10,11) all regressed -> this is the
// single-chain latency floor (~290 cyc/step) for the 1-wave/SIMD regime.
// ---------------------------------------------------------------------------
template<bool STORE4>
__global__ __launch_bounds__(64, 1) void hydro_scan(const float* __restrict__ x,
                                                    const float* __restrict__ raw,
                                                    float* __restrict__ qsim) {
    int tid = blockIdx.x * 64 + threadIdx.x;
    int g = tid % GPAD;
    int inst = tid / GPAD;
    if (g >= GG) return;
    int m = inst & 1;
    const float* pr = raw + (size_t)g * 38 + m;   // pr[2*i] = raw[g, i*2+m]

    int xoff = g * 3;
    int qoff = g + (STORE4 ? inst * QNI : 0);

    // prefetch pipeline: steps 0..PD-1
    float pb[PD], tb[PD], eb[PD];
#pragma unroll
    for (int j = 0; j < PD; ++j) {
        pb[j] = x[xoff]; tb[j] = x[xoff + 1]; eb[j] = x[xoff + 2];
        xoff += 3 * GG;
    }

    if (inst < 2) {
        // ---- HBV parameters (descale + derived constants) ----
        float beta  = 1.0f   + pr[0]  * 5.0f;
        float fc    = 50.0f  + pr[2]  * 950.0f;
        float k0    = 0.05f  + pr[4]  * 0.85f;
        float k1    = 0.01f  + pr[6]  * 0.49f;
        float k2    = 0.001f + pr[8]  * 0.199f;
        float lp    = 0.2f   + pr[10] * 0.8f;
        float perc  =          pr[12] * 10.0f;
        float uzl   =          pr[14] * 100.0f;
        float tt    = -2.5f  + pr[16] * 5.0f;
        float cfmax = 0.5f   + pr[18] * 9.5f;
        float cfr   =          pr[20] * 0.1f;
        float cwh   =          pr[22] * 0.2f;
        float invfc   = 1.0f / fc;
        float invlpfc = 1.0f / (lp * fc);
        float ncfrcf  = -(cfr * cfmax);
        float omk0    = 1.0f - k0;
        float k0uzl   = k0 * uzl;
        float omk1    = 1.0f - k1;

        float sp = 1e-5f, mw = 1e-5f, sm = 0.5f * fc, suz = 1e-5f, slz = 1e-5f;

        auto body = [&](float p, float tc, float pet) -> float {
            // off-chain (forcing-only) terms
            float dt   = tc - tt;
            float msn  = fmaxf(cfmax * dt, 0.0f);
            float mrf  = fmaxf(ncfrcf * dt, 0.0f);
            float rain = (dt >= 0.0f) ? p : 0.0f;
            float snow = p - rain;
            float etk  = fmaf(-invlpfc, pet, 1.0f);      // 1 - pet/(lp*fc)
            // long pole first: sw from previous-step sm
            float sw   = exp2f(beta * __log2f(sm * invfc));   // <= 1 (sm<=fc)
            float omsw = 1.0f - sw;
            // snow / melt-water chains
            float sp1  = sp + snow;
            float melt = fminf(msn, sp1);
            float mw2  = mw + melt;
            float sp2  = sp1 - melt;
            float refr = fminf(mrf, mw2);
            float mw3  = mw2 - refr;
            sp = sp2 + refr;
            float mw4  = fminf(mw3, cwh * sp);
            float tosoil = mw3 - mw4;
            mw = mw4;
            // soil moisture
            float rt    = rain + tosoil;
            float sm1   = fmaf(rt, omsw, sm);            // sm + rt - rech
            float rech  = rt * sw;
            float excess = fmaxf(sm1 - fc, 0.0f);
            float sm2   = fminf(sm1, fc);
            sm = fmaxf(fmaxf(sm2 * etk, sm2 - pet), 1e-5f);   // v_max3
            // upper / lower zones
            float suz1 = suz + rech + excess;
            float suz2 = fmaxf(suz1 - perc, 0.0f);
            float pa   = suz1 - suz2;                    // = min(perc, suz1)
            float suz3 = fminf(suz2, fmaf(suz2, omk0, k0uzl));
            float suzn = omk1 * suz3;
            float q01  = suz2 - suzn;                    // q0 + q1
            suz = suzn;
            float slz1 = slz + pa;
            float q2   = k2 * slz1;
            slz = slz1 - q2;
            return q01 + q2;
        };

        for (int c = 0; c < SS / PD - 1; ++c) {
#pragma unroll
            for (int j = 0; j < PD; ++j) {
                float p = pb[j], tc = tb[j], pet = eb[j];
                pb[j] = x[xoff]; tb[j] = x[xoff + 1]; eb[j] = x[xoff + 2];
                xoff += 3 * GG;
                float q = body(p, tc, pet);
                if (STORE4) qsim[qoff] = q; else atomicAdd(&qsim[qoff], 0.25f * q);
                qoff += GG;
            }
        }
#pragma unroll
        for (int j = 0; j < PD; ++j) {           // peeled last chunk
            float q = body(pb[j], tb[j], eb[j]);
            if (STORE4) qsim[qoff] = q; else atomicAdd(&qsim[qoff], 0.25f * q);
            qoff += GG;
        }
    } else {
        // ---- EXP-HYDRO parameters (descale + derived constants) ----
        const float* pe = pr + 24;
        float f    =           pe[0]  * 0.1f;
        float smax = 100.0f  + pe[2]  * 1400.0f;
        float qmax = 10.0f   + pe[4]  * 40.0f;
        float df   =           pe[6]  * 5.0f;
        float tmax =           pe[8]  * 3.0f;
        float tmin = -3.0f   + pe[10] * 3.0f;
        float invsmax = 1.0f / smax;
        float fl = f * 1.44269504f;              // f * log2(e)
        float c0 = __log2f(qmax) - fl * smax;    // fold qmax into exponent

        float s0 = 1e-5f, s1 = 0.5f * smax;

        auto body = [&](float p, float tc, float pet) -> float {
            // off-chain terms
            float mdf = df * fmaxf(tc - tmax, 0.0f);
            float ps  = (tc <= tmin) ? p : 0.0f;
            float prr = p - ps;
            float etk = fmaxf(fmaf(-invsmax, pet, 1.0f), 0.0f);
            // chains
            float mlt = fminf(s0, mdf);
            s0 = fmaxf(s0 - mdf, 0.0f) + ps;
            float s1a = s1 + prr + mlt;
            float qspill = fmaxf(s1a - smax, 0.0f);
            float s1b = fminf(s1a, smax);
            float s1c = s1b * etk;                       // s1b - et (exact)
            float qb  = fminf(exp2f(fmaf(fl, s1c, c0)), s1c);
            s1 = s1c - qb;
            return qspill + qb;
        };

        for (int c = 0; c < SS / PD - 1; ++c) {
#pragma unroll
            for (int j = 0; j < PD; ++j) {
                float p = pb[j], tc = tb[j], pet = eb[j];
                pb[j] = x[xoff]; tb[j] = x[xoff + 1]; eb[j] = x[xoff + 2];
                xoff += 3 * GG;
                float q = body(p, tc, pet);
                if (STORE4) qsim[qoff] = q; else atomicAdd(&qsim[qoff], 0.25f * q);
                qoff += GG;
            }
        }
#pragma unroll
        for (int j = 0; j < PD; ++j) {
            float q = body(pb[j], tb[j], eb[j]);
            if (STORE4) qsim[qoff] = q; else atomicAdd(&qsim[qoff], 0.25f * q);
            qoff += GG;
        }
    }
}

// ---------------------------------------------------------------------------
// UH weights: one thread per g, 15 normalized gamma-UH weights once (0.25
// folded). gammaln cancels: w[k] ∝ exp((aa-1)ln(k+.5)-(k+.5)/th).
// ---------------------------------------------------------------------------
__global__ __launch_bounds__(256) void uh_weights(const float* __restrict__ raw,
                                                  float* __restrict__ wbuf) {
    int g = blockIdx.x * 256 + threadIdx.x;
    if (g >= GG) return;
    float a = raw[(size_t)g * 38 + 36] * 2.9f;
    float b = raw[(size_t)g * 38 + 37] * 6.5f;
    float aa = fmaxf(a, 0.0f) + 0.1f;
    float th = fmaxf(b, 0.0f) + 0.5f;
    float am1 = aa - 1.0f;
    float invth = 1.0f / th;

    const float logt[LENF] = {
        -0.69314718f, 0.40546511f, 0.91629073f, 1.25276297f, 1.50407740f,
         1.70474809f, 1.87180218f, 2.01490302f, 2.14006616f, 2.25129180f,
         2.35137526f, 2.44234704f, 2.52572864f, 2.60268969f, 2.67414865f };

    float w[LENF];
    float s = 0.0f;
#pragma unroll
    for (int k = 0; k < LENF; ++k) {
        float tk = (float)k + 0.5f;
        w[k] = expf(am1 * logt[k] - tk * invth);
        s += w[k];
    }
    float scale = 0.25f / s;
#pragma unroll
    for (int k = 0; k < LENF; ++k)
        wbuf[(size_t)k * GG + g] = w[k] * scale;
}

// ---------------------------------------------------------------------------
// Routing kernel, big time-tile TT=73: each thread owns one g and 73
// consecutive t's, so each qsim value is read only 87/73 = 1.19x per slice
// (was 2.4x at TT=10) -> route read traffic ~56 MB instead of ~112 MB.
// WPRE: weights preloaded from wbuf (0.25/s folded). NB = #slices summed.
// ---------------------------------------------------------------------------
template<int NB, bool WPRE>
__global__ __launch_bounds__(256) void hydro_route(const float* __restrict__ qsim,
                                                   const float* __restrict__ raw,
                                                   const float* __restrict__ wbuf,
                                                   float* __restrict__ out) {
    int idx = blockIdx.x * 256 + threadIdx.x;
    if (idx >= GG * (SS / TT)) return;
    int g = idx % GG;          // g fast -> coalesced
    int c = idx / GG;
    int t0 = c * TT;

    float w[LENF];
    float scale;
    if (WPRE) {
#pragma unroll
        for (int k = 0; k < LENF; ++k)
            w[k] = wbuf[(size_t)k * GG + g];
        scale = 1.0f;
    } else {
        float a = raw[(size_t)g * 38 + 36] * 2.9f;
        float b = raw[(size_t)g * 38 + 37] * 6.5f;
        float aa = fmaxf(a, 0.0f) + 0.1f;
        float th = fmaxf(b, 0.0f) + 0.5f;
        float am1 = aa - 1.0f;
        float invth = 1.0f / th;
        const float logt[LENF] = {
            -0.69314718f, 0.40546511f, 0.91629073f, 1.25276297f, 1.50407740f,
             1.70474809f, 1.87180218f, 2.01490302f, 2.14006616f, 2.25129180f,
             2.35137526f, 2.44234704f, 2.52572864f, 2.60268969f, 2.67414865f };
        float s = 0.0f;
#pragma unroll
        for (int k = 0; k < LENF; ++k) {
            float tk = (float)k + 0.5f;
            w[k] = expf(am1 * logt[k] - tk * invth);
            s += w[k];
        }
        scale = (NB == 4 ? 0.25f : 1.0f) / s;
    }

    // load qsim[t0-14 .. t0+TT-1] (zeros before t=0), summing NB slices
    float v[TT + LENF - 1];
#pragma unroll
    for (int i = 0; i < TT + LENF - 1; ++i) {
        int tp = t0 - (LENF - 1) + i;
        float sv = 0.0f;
        if (tp >= 0) {
            const float* qb = qsim + (size_t)tp * GG + g;
            sv = qb[0];
            if (NB == 4) sv += qb[QN] + qb[2 * QN] + qb[3 * QN];
        }
        v[i] = sv;
    }
#pragma unroll
    for (int j = 0; j < TT; ++j) {
        float acc = 0.0f;
#pragma unroll
        for (int k = 0; k < LENF; ++k)
            acc += w[k] * v[j + (LENF - 1) - k];
        out[(size_t)(t0 + j) * GG + g] = (WPRE ? acc : acc * scale);
    }
}

// ---------------------------------------------------------------------------
extern "C" void kernel_launch(void* const* d_in, const int* in_sizes, int n_in,
                              void* d_out, int out_size, void* d_ws, size_t ws_size,
                              hipStream_t stream) {
    const float* x   = (const float*)d_in[0];   // (730, 4000, 3) f32
    const float* raw = (const float*)d_in[1];   // (4000, 38) f32
    float* out  = (float*)d_out;                // (730, 4000) f32
    float* qsim = (float*)d_ws;

    const size_t slices4 = 4 * QN * sizeof(float);
    const size_t wbytes  = (size_t)LENF * GG * sizeof(float);
    int rblocks = (GG * (SS / TT) + 255) / 256;
    int sblocks = (4 * GPAD) / 64;

    if (ws_size >= slices4 + wbytes) {
        float* wbuf = qsim + 4 * QN;
        hydro_scan<true><<<sblocks, 64, 0, stream>>>(x, raw, qsim);
        uh_weights<<<(GG + 255) / 256, 256, 0, stream>>>(raw, wbuf);
        hydro_route<4, true><<<rblocks, 256, 0, stream>>>(qsim, raw, wbuf, out);
    } else {
        hipMemsetAsync(qsim, 0, QN * sizeof(float), stream);
        hydro_scan<false><<<sblocks, 64, 0, stream>>>(x, raw, qsim);
        hydro_route<1, false><<<rblocks, 256, 0, stream>>>(qsim, raw, nullptr, out);
    }
}